// Round 5
// baseline (561.281 us; speedup 1.0000x reference)
//
#include <hip/hip_runtime.h>

// VisualDepthAttention on MI355X (gfx950) — round 7.
// R6 post-mortem: total 550 (best) but kernel 343->384: inlined staging kept the
// read-optimal float4 mapping and paid 13.9M LDS conflict cycles on 16 scalar
// u16 writes/thread (512B lane stride -> same-bank serialization).
// R7: write-optimal staging. Frag-linear is byte-linear: group g (8 j-elements) ->
// &xs[g*8], one ds_write_b128, consecutive lanes -> consecutive 16B (mirror of the
// conflict-free GEMM read). Reads: 8 scalar floats from one row (32B/lane contiguous,
// 16 rows x 128B per wave). Invalid cols write 0 -> xs pre-zero + S0 barrier deleted.
// Everything else identical to R6 (prefetch structure, layouts, attention math).

#define D1    257
#define NTOK  64
#define KT    9      // K padded to 288 = 9*32
#define NT_CAT 49    // Wcat N = 784 = 49*16
#define NT_OUT 17    // Wout N = 272 = 17*16
#define SCALE 0.17677669529663687f

// ---- fused kernel LDS layout (frag-linear). Total 154,624 <= 163,840 ----
#define XS2_OFF 0          // xs/oc: 36 frags x 1KB = 36,864 (frag = kt*4+mt)
#define QS2_OFF 36864      // qs: 32 frags x 1KB = 32,768; at overlay (16w x 2,176 = 34,816)
#define KS2_OFF 71680      // ks: 32 frags = 32,768
#define VS2_OFF 104448     // vs: 32 frags = 32,768 (B-frag-linear)
#define DS2_OFF 137216     // dsum fp32 [64][65] = 16,640
#define QD2_OFF 153856
#define KD2_OFF 154112
#define VD2_OFF 154368
#define LDS2    154624
#define AT_STRIDE 68
#define DS_STRIDE 65

#define WCAT_ELEMS (KT * NT_CAT * 512)   // 225792 bf16
#define WOUT_ELEMS (KT * NT_OUT * 512)   // 78336 bf16

using bf16x8 = __attribute__((ext_vector_type(8))) short;
using s16x4  = __attribute__((ext_vector_type(4))) short;
using f32x4  = __attribute__((ext_vector_type(4))) float;

__device__ __forceinline__ short f2b(float f) {
  unsigned u = __float_as_uint(f);
  u = (u + 0x7FFFu + ((u >> 16) & 1u)) >> 16;   // RNE
  return (short)u;
}

__device__ __forceinline__ f32x4 mfma16(bf16x8 a, bf16x8 b, f32x4 c) {
  return __builtin_amdgcn_mfma_f32_16x16x32_bf16(a, b, c, 0, 0, 0);
}

// B-fragment load macros (16B/lane, lane-linear -> coalesced, conflict-free)
#define WFRAG(kt, nt) (*(const bf16x8*)(wcatp + ((size_t)((kt) * NT_CAT + (nt)) * 64 + lane) * 8))
#define OFRAG(kt, nt) (*(const bf16x8*)(woutp + ((size_t)((kt) * NT_OUT + (nt)) * 64 + lane) * 8))

__global__ void prep_weights(const float* __restrict__ Wqv, const float* __restrict__ Wkv,
                             const float* __restrict__ Wvv, const float* __restrict__ Wqd,
                             const float* __restrict__ Wkd, const float* __restrict__ Wvd,
                             const float* __restrict__ Wout,
                             short* __restrict__ wcatp, short* __restrict__ woutp) {
  int idx = blockIdx.x * 256 + threadIdx.x;
  if (idx < WCAT_ELEMS) {
    int j = idx & 7, lane = (idx >> 3) & 63, rest = idx >> 9;
    int nt = rest % NT_CAT, kt = rest / NT_CAT;
    int k = 32 * kt + (lane >> 4) * 8 + j;
    int n = 16 * nt + (lane & 15);
    float v = 0.f;
    if (k < D1) {
      if (n < 256)       v = Wqv[k * 256 + n] * SCALE;
      else if (n < 512)  v = Wkv[k * 256 + (n - 256)];
      else if (n < 768)  v = Wvv[k * 256 + (n - 512)];
      else if (n == 768) v = Wqd[k] * SCALE;
      else if (n == 769) v = Wkd[k];
      else if (n == 770) v = Wvd[k];
    }
    wcatp[idx] = f2b(v);
  } else {
    int i2 = idx - WCAT_ELEMS;
    int j = i2 & 7, lane = (i2 >> 3) & 63, rest = i2 >> 9;
    int nt = rest % NT_OUT, kt = rest / NT_OUT;
    int k = 32 * kt + (lane >> 4) * 8 + j;
    int n = 16 * nt + (lane & 15);
    float v = (k < D1 && n < D1) ? Wout[k * D1 + n] : 0.f;
    woutp[i2] = f2b(v);
  }
}

// ======================= R7 fused kernel =======================
__global__ __launch_bounds__(1024)
void vda_attn2(const float* __restrict__ x, const short* __restrict__ wcatp,
               const short* __restrict__ woutp, float* __restrict__ out) {
  extern __shared__ char smem[];
  short* xs   = (short*)(smem + XS2_OFF);
  short* qs   = (short*)(smem + QS2_OFF);
  short* ks   = (short*)(smem + KS2_OFF);
  short* vs   = (short*)(smem + VS2_OFF);
  float* dsum = (float*)(smem + DS2_OFF);
  float* qd_s = (float*)(smem + QD2_OFF);
  float* kd_s = (float*)(smem + KD2_OFF);
  float* vd_s = (float*)(smem + VD2_OFF);
  short* oc = xs;

  const int tid  = threadIdx.x;
  const int lane = tid & 63;
  const int w    = tid >> 6;        // wave 0..15
  const int m    = lane & 15;
  const int q    = lane >> 4;
  const int q8   = q * 8;
  const int win  = blockIdx.x;

  // Pre-issue pass-0 B-frags (kt=0,1) at kernel start: the entire staging phase
  // hides their latency.
  bf16x8 bA0 = WFRAG(0, w),      bA1 = WFRAG(1, w);
  bf16x8 bB0 = WFRAG(0, w + 16), bB1 = WFRAG(1, w + 16);

  // ---- Phase A: stage x write-optimally. Group g in [0,2304): dest = &xs[g*8]
  // (16B, lane-linear -> conflict-free). Decode: frag = g>>6, row = ((g>>6)&3)*16 +
  // (g&15), col0 = (g>>8)*32 + ((g>>4)&3)*8. cols >= 257 write 0 (covers K-pad;
  // no pre-zero pass, no extra barrier). Also zero dsum (ordered by S1).
  {
    const float* xw = x + (size_t)win * (NTOK * D1);
    for (int g = tid; g < 2304; g += 1024) {
      int row  = ((g >> 6) & 3) * 16 + (g & 15);
      int col0 = (g >> 8) * 32 + ((g >> 4) & 3) * 8;
      const float* src = xw + row * D1 + col0;
      bf16x8 pk;
#pragma unroll
      for (int jj = 0; jj < 8; ++jj) {
        float v = (col0 + jj < D1) ? src[jj] : 0.f;
        pk[jj] = f2b(v);
      }
      *(bf16x8*)&xs[g * 8] = pk;
    }
  }
  for (int i = tid; i < 64 * DS_STRIDE; i += 1024) dsum[i] = 0.f;
  __syncthreads();   // S1

  // ---- Phase B: C = xs[64x288] @ Wcat[288x784]. Two nt-passes, acc[2][4] (32 AGPR),
  // 2-deep global B-frag prefetch + 1-deep LDS A-frag prefetch.
  {
    // ================= pass 0: ntA = w (-> Q), ntB = w+16 (-> K) =================
    f32x4 acc[2][4];
#pragma unroll
    for (int t = 0; t < 2; ++t)
#pragma unroll
      for (int mt = 0; mt < 4; ++mt) acc[t][mt] = f32x4{0.f, 0.f, 0.f, 0.f};

    bf16x8 a_c[4];
#pragma unroll
    for (int mt = 0; mt < 4; ++mt)
      a_c[mt] = *(const bf16x8*)&xs[mt * 512 + lane * 8];

#pragma unroll
    for (int kt = 0; kt < KT; ++kt) {
      bf16x8 bA2{}, bB2{};
      if (kt + 2 < KT) {
        bA2 = WFRAG(kt + 2, w);
        bB2 = WFRAG(kt + 2, w + 16);
      }
      bf16x8 a_n[4];
      if (kt + 1 < KT) {
#pragma unroll
        for (int mt = 0; mt < 4; ++mt)
          a_n[mt] = *(const bf16x8*)&xs[((kt + 1) * 4 + mt) * 512 + lane * 8];
      }
#pragma unroll
      for (int mt = 0; mt < 4; ++mt) acc[0][mt] = mfma16(a_c[mt], bA0, acc[0][mt]);
#pragma unroll
      for (int mt = 0; mt < 4; ++mt) acc[1][mt] = mfma16(a_c[mt], bB0, acc[1][mt]);
      bA0 = bA1; bA1 = bA2; bB0 = bB1; bB1 = bB2;
      if (kt + 1 < KT) {
#pragma unroll
        for (int mt = 0; mt < 4; ++mt) a_c[mt] = a_n[mt];
      }
    }

    // Issue pass-1 prefetch now (overlaps pass-0 epilogue LDS writes).
    bf16x8 cA0 = WFRAG(0, w + 32), cA1 = WFRAG(1, w + 32);
    bf16x8 cB0{}, cB1{};
    if (w == 0) { cB0 = WFRAG(0, 48); cB1 = WFRAG(1, 48); }

    // pass-0 epilogue: Q (acc[0]) and K (acc[1]), frag-linear.
    {
      int cq = (2 * w + (m >> 3)) & 3;
      int jj = m & 7;
      int fb = (w >> 1) * 4;
#pragma unroll
      for (int mt = 0; mt < 4; ++mt)
#pragma unroll
        for (int r = 0; r < 4; ++r)
          qs[(fb + mt) * 512 + (cq * 16 + 4 * q + r) * 8 + jj] = f2b(acc[0][mt][r]);
#pragma unroll
      for (int mt = 0; mt < 4; ++mt)
#pragma unroll
        for (int r = 0; r < 4; ++r)
          ks[(fb + mt) * 512 + (cq * 16 + 4 * q + r) * 8 + jj] = f2b(acc[1][mt][r]);
    }

    // ================= pass 1: ntA = w+32 (-> V), ntB = 48 (w==0 -> depth) =================
#pragma unroll
    for (int t = 0; t < 2; ++t)
#pragma unroll
      for (int mt = 0; mt < 4; ++mt) acc[t][mt] = f32x4{0.f, 0.f, 0.f, 0.f};

#pragma unroll
    for (int mt = 0; mt < 4; ++mt)
      a_c[mt] = *(const bf16x8*)&xs[mt * 512 + lane * 8];

#pragma unroll
    for (int kt = 0; kt < KT; ++kt) {
      bf16x8 cA2{}, cB2{};
      if (kt + 2 < KT) {
        cA2 = WFRAG(kt + 2, w + 32);
        if (w == 0) cB2 = WFRAG(kt + 2, 48);
      }
      bf16x8 a_n[4];
      if (kt + 1 < KT) {
#pragma unroll
        for (int mt = 0; mt < 4; ++mt)
          a_n[mt] = *(const bf16x8*)&xs[((kt + 1) * 4 + mt) * 512 + lane * 8];
      }
#pragma unroll
      for (int mt = 0; mt < 4; ++mt) acc[0][mt] = mfma16(a_c[mt], cA0, acc[0][mt]);
      if (w == 0) {
#pragma unroll
        for (int mt = 0; mt < 4; ++mt) acc[1][mt] = mfma16(a_c[mt], cB0, acc[1][mt]);
      }
      cA0 = cA1; cA1 = cA2; cB0 = cB1; cB1 = cB2;
      if (kt + 1 < KT) {
#pragma unroll
        for (int mt = 0; mt < 4; ++mt) a_c[mt] = a_n[mt];
      }
    }

    // pass-1 epilogue: V B-frag-linear (proven layout)
#pragma unroll
    for (int mt = 0; mt < 4; ++mt) {
      int frag = w * 2 + (mt >> 1);
      int q2 = (2 * mt + (q >> 1)) & 3;
      int j0 = 4 * (q & 1);
      s16x4 pk;
#pragma unroll
      for (int r = 0; r < 4; ++r) pk[r] = f2b(acc[0][mt][r]);
      *(s16x4*)&vs[frag * 512 + (q2 * 16 + m) * 8 + j0] = pk;
    }
    // depth cols 768..770 (w==0 only)
    if (w == 0 && m < 3) {
      float* dst = (m == 0) ? qd_s : (m == 1) ? kd_s : vd_s;
#pragma unroll
      for (int mt = 0; mt < 4; ++mt)
#pragma unroll
        for (int r = 0; r < 4; ++r)
          dst[16 * mt + 4 * q + r] = acc[1][mt][r];
    }
  }
  __syncthreads();   // S2

  // ---- Phase C: wave = (rw = w&3 row tile, hp = w>>2 head pair {2hp, 2hp+1}).
  const int rw = w & 3;
  const int hp = w >> 2;

  bf16x8 aq[2];
#pragma unroll
  for (int hh = 0; hh < 2; ++hh)
    aq[hh] = *(const bf16x8*)&qs[(((2 * hp + hh) * 4 + rw)) * 512 + lane * 8];

  float gate[4][4], ssum[4][4];
  {
    float qd_r[4], kd_c[4];
#pragma unroll
    for (int r = 0; r < 4; ++r) qd_r[r] = qd_s[16 * rw + 4 * q + r];
#pragma unroll
    for (int nt = 0; nt < 4; ++nt) kd_c[nt] = kd_s[16 * nt + m];
#pragma unroll
    for (int nt = 0; nt < 4; ++nt)
#pragma unroll
      for (int r = 0; r < 4; ++r) {
        float t = qd_r[r] * kd_c[nt];
        gate[nt][r] = 1.f / (1.f + __expf(-t));
        ssum[nt][r] = 0.f;
      }
  }
  __syncthreads();   // S3 (qs dead -> at overlay live; oc (over xs) writable)

  if (hp == 0) {     // zero oc pad frags 32..35 (cols 256..287)
    int4 z4; z4.x = 0; z4.y = 0; z4.z = 0; z4.w = 0;
    ((int4*)(oc + 32 * 512))[rw * 64 + lane] = z4;
  }

  short* atw = (short*)(smem + QS2_OFF) + w * (16 * AT_STRIDE);

#pragma unroll
  for (int hh = 0; hh < 2; ++hh) {
    int h = 2 * hp + hh;
    f32x4 sv[4];
#pragma unroll
    for (int nt = 0; nt < 4; ++nt) {
      bf16x8 bk = *(const bf16x8*)&ks[(h * 4 + nt) * 512 + lane * 8];
      f32x4 z = {0.f, 0.f, 0.f, 0.f};
      sv[nt] = mfma16(aq[hh], bk, z);
    }
    float sm[4][4], mx[4], sum[4];
#pragma unroll
    for (int r = 0; r < 4; ++r) mx[r] = -3.4e38f;
#pragma unroll
    for (int nt = 0; nt < 4; ++nt)
#pragma unroll
      for (int r = 0; r < 4; ++r) {
        float s = sv[nt][r] * gate[nt][r];
        ssum[nt][r] += s;
        sm[nt][r] = s;
        mx[r] = fmaxf(mx[r], s);
      }
#pragma unroll
    for (int r = 0; r < 4; ++r) {
#pragma unroll
      for (int msk = 1; msk < 16; msk <<= 1)
        mx[r] = fmaxf(mx[r], __shfl_xor(mx[r], msk));
      sum[r] = 0.f;
    }
#pragma unroll
    for (int nt = 0; nt < 4; ++nt)
#pragma unroll
      for (int r = 0; r < 4; ++r) {
        float p = __expf(sm[nt][r] - mx[r]);
        sm[nt][r] = p;
        sum[r] += p;
      }
#pragma unroll
    for (int r = 0; r < 4; ++r) {
#pragma unroll
      for (int msk = 1; msk < 16; msk <<= 1)
        sum[r] += __shfl_xor(sum[r], msk);
      sum[r] = 1.f / sum[r];
    }
#pragma unroll
    for (int nt = 0; nt < 4; ++nt)
#pragma unroll
      for (int r = 0; r < 4; ++r)
        atw[(4 * q + r) * AT_STRIDE + 16 * nt + m] = f2b(sm[nt][r] * sum[r]);

    // A-frags of attn (wave-private LDS round trip)
    s16x4 l0 = *(const s16x4*)&atw[m * AT_STRIDE + q8];
    s16x4 l1 = *(const s16x4*)&atw[m * AT_STRIDE + q8 + 4];
    s16x4 l2 = *(const s16x4*)&atw[m * AT_STRIDE + 32 + q8];
    s16x4 l3 = *(const s16x4*)&atw[m * AT_STRIDE + 32 + q8 + 4];
    bf16x8 a0, a1;
#pragma unroll
    for (int j = 0; j < 4; ++j) { a0[j] = l0[j]; a0[4 + j] = l1[j]; a1[j] = l2[j]; a1[4 + j] = l3[j]; }

#pragma unroll
    for (int ntv = 0; ntv < 2; ++ntv) {
      bf16x8 bv0 = *(const bf16x8*)&vs[(((2 * h + ntv) * 2) + 0) * 512 + lane * 8];
      bf16x8 bv1 = *(const bf16x8*)&vs[(((2 * h + ntv) * 2) + 1) * 512 + lane * 8];
      f32x4 o = {0.f, 0.f, 0.f, 0.f};
      o = mfma16(a0, bv0, o);
      o = mfma16(a1, bv1, o);
      // oc frag-linear write: row=16rw+4q+r, col=32h+16ntv+m
      int cq2 = (2 * ntv + (m >> 3)) & 3;
#pragma unroll
      for (int r = 0; r < 4; ++r)
        oc[(h * 4 + rw) * 512 + (cq2 * 16 + 4 * q + r) * 8 + (m & 7)] = f2b(o[r]);
    }
  }

  // head-sum reduction across the 4 hp-waves sharing rw
#pragma unroll
  for (int nt = 0; nt < 4; ++nt)
#pragma unroll
    for (int r = 0; r < 4; ++r)
      atomicAdd(&dsum[(16 * rw + 4 * q + r) * DS_STRIDE + 16 * nt + m], ssum[nt][r]);
  __syncthreads();   // S5

  if (hp == 0) {     // attn_d softmax + out_d for rows 16rw..16rw+15
    float sd[4][4], mx[4], sum[4];
#pragma unroll
    for (int nt = 0; nt < 4; ++nt)
#pragma unroll
      for (int r = 0; r < 4; ++r)
        sd[nt][r] = dsum[(16 * rw + 4 * q + r) * DS_STRIDE + 16 * nt + m];
#pragma unroll
    for (int r = 0; r < 4; ++r) mx[r] = -3.4e38f;
#pragma unroll
    for (int nt = 0; nt < 4; ++nt)
#pragma unroll
      for (int r = 0; r < 4; ++r) mx[r] = fmaxf(mx[r], sd[nt][r]);
#pragma unroll
    for (int r = 0; r < 4; ++r) {
#pragma unroll
      for (int msk = 1; msk < 16; msk <<= 1)
        mx[r] = fmaxf(mx[r], __shfl_xor(mx[r], msk));
      sum[r] = 0.f;
    }
#pragma unroll
    for (int nt = 0; nt < 4; ++nt)
#pragma unroll
      for (int r = 0; r < 4; ++r) {
        sd[nt][r] = __expf(sd[nt][r] - mx[r]);
        sum[r] += sd[nt][r];
      }
#pragma unroll
    for (int r = 0; r < 4; ++r) {
#pragma unroll
      for (int msk = 1; msk < 16; msk <<= 1)
        sum[r] += __shfl_xor(sum[r], msk);
      sum[r] = 1.f / sum[r];
    }
    float vd_c[4];
#pragma unroll
    for (int nt = 0; nt < 4; ++nt) vd_c[nt] = vd_s[16 * nt + m];
    float ov[4] = {0.f, 0.f, 0.f, 0.f};
#pragma unroll
    for (int nt = 0; nt < 4; ++nt)
#pragma unroll
      for (int r = 0; r < 4; ++r) ov[r] += sd[nt][r] * vd_c[nt];
#pragma unroll
    for (int r = 0; r < 4; ++r) {
#pragma unroll
      for (int msk = 1; msk < 16; msk <<= 1)
        ov[r] += __shfl_xor(ov[r], msk);
    }
    if (m == 0) {
      // col 256 -> frag 32+rw, cq=0, j=0
#pragma unroll
      for (int r = 0; r < 4; ++r)
        oc[(32 + rw) * 512 + (4 * q + r) * 8] = f2b(ov[r] * sum[r]);
    }
  }

  // Pre-issue phase-D B-frags (kt=0,1) BEFORE S6: barrier drain hides their latency.
  bf16x8 dA0 = OFRAG(0, w), dA1 = OFRAG(1, w);
  bf16x8 dB0{}, dB1{};
  if (w == 0) { dB0 = OFRAG(0, 16); dB1 = OFRAG(1, 16); }
  __syncthreads();   // S6

  // ---- Phase D: out = oc[64x288] @ Wout[288x272]; wave w owns nt {w, 16 (w==0)}.
  // 2-deep global prefetch + 1-deep LDS A-frag prefetch.
  {
    f32x4 acc2[2][4];
#pragma unroll
    for (int t = 0; t < 2; ++t)
#pragma unroll
      for (int mt = 0; mt < 4; ++mt) acc2[t][mt] = f32x4{0.f, 0.f, 0.f, 0.f};

    bf16x8 ao_c[4];
#pragma unroll
    for (int mt = 0; mt < 4; ++mt)
      ao_c[mt] = *(const bf16x8*)&oc[mt * 512 + lane * 8];

#pragma unroll
    for (int kt = 0; kt < KT; ++kt) {
      bf16x8 dA2{}, dB2{};
      if (kt + 2 < KT) {
        dA2 = OFRAG(kt + 2, w);
        if (w == 0) dB2 = OFRAG(kt + 2, 16);
      }
      bf16x8 ao_n[4];
      if (kt + 1 < KT) {
#pragma unroll
        for (int mt = 0; mt < 4; ++mt)
          ao_n[mt] = *(const bf16x8*)&oc[((kt + 1) * 4 + mt) * 512 + lane * 8];
      }
#pragma unroll
      for (int mt = 0; mt < 4; ++mt) acc2[0][mt] = mfma16(ao_c[mt], dA0, acc2[0][mt]);
      if (w == 0) {
#pragma unroll
        for (int mt = 0; mt < 4; ++mt) acc2[1][mt] = mfma16(ao_c[mt], dB0, acc2[1][mt]);
      }
      dA0 = dA1; dA1 = dA2; dB0 = dB1; dB1 = dB2;
      if (kt + 1 < KT) {
#pragma unroll
        for (int mt = 0; mt < 4; ++mt) ao_c[mt] = ao_n[mt];
      }
    }

    // epilogue: t=0 -> n = 16w+m (always < 256); t=1 (w==0) -> n = 256 (m==0 only)
    {
      int n = 16 * w + m;
#pragma unroll
      for (int mt = 0; mt < 4; ++mt)
#pragma unroll
        for (int r = 0; r < 4; ++r)
          out[((size_t)win * NTOK + 16 * mt + 4 * q + r) * D1 + n] = acc2[0][mt][r];
    }
    if (w == 0 && m == 0) {
#pragma unroll
      for (int mt = 0; mt < 4; ++mt)
#pragma unroll
        for (int r = 0; r < 4; ++r)
          out[((size_t)win * NTOK + 16 * mt + 4 * q + r) * D1 + 256] = acc2[1][mt][r];
    }
  }
}

extern "C" void kernel_launch(void* const* d_in, const int* in_sizes, int n_in,
                              void* d_out, int out_size, void* d_ws, size_t ws_size,
                              hipStream_t stream) {
  (void)n_in; (void)out_size; (void)ws_size;
  const float* x    = (const float*)d_in[0];
  const float* Wqv  = (const float*)d_in[1];
  const float* Wkv  = (const float*)d_in[2];
  const float* Wvv  = (const float*)d_in[3];
  const float* Wqd  = (const float*)d_in[4];
  const float* Wkd  = (const float*)d_in[5];
  const float* Wvd  = (const float*)d_in[6];
  const float* Wout = (const float*)d_in[7];
  float* out = (float*)d_out;

  short* wcatp = (short*)d_ws;                  // 608,256 B total for weights
  short* woutp = wcatp + WCAT_ELEMS;

  int nwin = in_sizes[0] / (NTOK * D1);         // 2048

  int prep_blocks = (WCAT_ELEMS + WOUT_ELEMS) / 256;   // 1188, exact
  prep_weights<<<prep_blocks, 256, 0, stream>>>(Wqv, Wkv, Wvv, Wqd, Wkd, Wvd, Wout, wcatp, woutp);

  hipFuncSetAttribute((const void*)vda_attn2, hipFuncAttributeMaxDynamicSharedMemorySize, LDS2);
  vda_attn2<<<nwin, 1024, LDS2, stream>>>(x, wcatp, woutp, out);
}

// Round 6
// 543.841 us; speedup vs baseline: 1.0321x; 1.0321x over previous
//
#include <hip/hip_runtime.h>

// VisualDepthAttention on MI355X (gfx950) — round 8.
// R7 post-mortem: conflicts 17.9M->4.06M as predicted, but kernel 384->401: the
// per-element OOB guard (col0+jj<D1 ? src[jj] : 0) forced 18 exec-guarded scalar
// loads/thread — VMEM issue overhead exceeded the conflict saving (VALUBusy fell
// 25.9->21.8 = more stall).
// R8: group-level branch, all paths provably in-bounds, no per-element predication:
//   col0<=248 -> 8 unconditional loads (compiler can merge; max off 16446 < 16448)
//   col0==256 -> 1 load (off<=16447) + 7 zeros
//   col0 in {264,272,280} -> zeros (only finiteness required: Wcat rows k>=257 are
//   zero, so pad A-values multiply by 0; zeros because fresh LDS may hold NaN bits)
// Also deleted the redundant hp==0 oc-pad zeroing (staging zero-fills frags 32..35,
// PV never writes them, out_d overwrites the k=256 column before phase D reads).
// Everything else identical to R7.

#define D1    257
#define NTOK  64
#define KT    9      // K padded to 288 = 9*32
#define NT_CAT 49    // Wcat N = 784 = 49*16
#define NT_OUT 17    // Wout N = 272 = 17*16
#define SCALE 0.17677669529663687f

// ---- fused kernel LDS layout (frag-linear). Total 154,624 <= 163,840 ----
#define XS2_OFF 0          // xs/oc: 36 frags x 1KB = 36,864 (frag = kt*4+mt)
#define QS2_OFF 36864      // qs: 32 frags x 1KB = 32,768; at overlay (16w x 2,176 = 34,816)
#define KS2_OFF 71680      // ks: 32 frags = 32,768
#define VS2_OFF 104448     // vs: 32 frags = 32,768 (B-frag-linear)
#define DS2_OFF 137216     // dsum fp32 [64][65] = 16,640
#define QD2_OFF 153856
#define KD2_OFF 154112
#define VD2_OFF 154368
#define LDS2    154624
#define AT_STRIDE 68
#define DS_STRIDE 65

#define WCAT_ELEMS (KT * NT_CAT * 512)   // 225792 bf16
#define WOUT_ELEMS (KT * NT_OUT * 512)   // 78336 bf16

using bf16x8 = __attribute__((ext_vector_type(8))) short;
using s16x4  = __attribute__((ext_vector_type(4))) short;
using f32x4  = __attribute__((ext_vector_type(4))) float;

__device__ __forceinline__ short f2b(float f) {
  unsigned u = __float_as_uint(f);
  u = (u + 0x7FFFu + ((u >> 16) & 1u)) >> 16;   // RNE
  return (short)u;
}

__device__ __forceinline__ f32x4 mfma16(bf16x8 a, bf16x8 b, f32x4 c) {
  return __builtin_amdgcn_mfma_f32_16x16x32_bf16(a, b, c, 0, 0, 0);
}

// B-fragment load macros (16B/lane, lane-linear -> coalesced, conflict-free)
#define WFRAG(kt, nt) (*(const bf16x8*)(wcatp + ((size_t)((kt) * NT_CAT + (nt)) * 64 + lane) * 8))
#define OFRAG(kt, nt) (*(const bf16x8*)(woutp + ((size_t)((kt) * NT_OUT + (nt)) * 64 + lane) * 8))

__global__ void prep_weights(const float* __restrict__ Wqv, const float* __restrict__ Wkv,
                             const float* __restrict__ Wvv, const float* __restrict__ Wqd,
                             const float* __restrict__ Wkd, const float* __restrict__ Wvd,
                             const float* __restrict__ Wout,
                             short* __restrict__ wcatp, short* __restrict__ woutp) {
  int idx = blockIdx.x * 256 + threadIdx.x;
  if (idx < WCAT_ELEMS) {
    int j = idx & 7, lane = (idx >> 3) & 63, rest = idx >> 9;
    int nt = rest % NT_CAT, kt = rest / NT_CAT;
    int k = 32 * kt + (lane >> 4) * 8 + j;
    int n = 16 * nt + (lane & 15);
    float v = 0.f;
    if (k < D1) {
      if (n < 256)       v = Wqv[k * 256 + n] * SCALE;
      else if (n < 512)  v = Wkv[k * 256 + (n - 256)];
      else if (n < 768)  v = Wvv[k * 256 + (n - 512)];
      else if (n == 768) v = Wqd[k] * SCALE;
      else if (n == 769) v = Wkd[k];
      else if (n == 770) v = Wvd[k];
    }
    wcatp[idx] = f2b(v);
  } else {
    int i2 = idx - WCAT_ELEMS;
    int j = i2 & 7, lane = (i2 >> 3) & 63, rest = i2 >> 9;
    int nt = rest % NT_OUT, kt = rest / NT_OUT;
    int k = 32 * kt + (lane >> 4) * 8 + j;
    int n = 16 * nt + (lane & 15);
    float v = (k < D1 && n < D1) ? Wout[k * D1 + n] : 0.f;
    woutp[i2] = f2b(v);
  }
}

// ======================= R8 fused kernel =======================
__global__ __launch_bounds__(1024)
void vda_attn2(const float* __restrict__ x, const short* __restrict__ wcatp,
               const short* __restrict__ woutp, float* __restrict__ out) {
  extern __shared__ char smem[];
  short* xs   = (short*)(smem + XS2_OFF);
  short* qs   = (short*)(smem + QS2_OFF);
  short* ks   = (short*)(smem + KS2_OFF);
  short* vs   = (short*)(smem + VS2_OFF);
  float* dsum = (float*)(smem + DS2_OFF);
  float* qd_s = (float*)(smem + QD2_OFF);
  float* kd_s = (float*)(smem + KD2_OFF);
  float* vd_s = (float*)(smem + VD2_OFF);
  short* oc = xs;

  const int tid  = threadIdx.x;
  const int lane = tid & 63;
  const int w    = tid >> 6;        // wave 0..15
  const int m    = lane & 15;
  const int q    = lane >> 4;
  const int q8   = q * 8;
  const int win  = blockIdx.x;

  // Pre-issue pass-0 B-frags (kt=0,1) at kernel start: the entire staging phase
  // hides their latency.
  bf16x8 bA0 = WFRAG(0, w),      bA1 = WFRAG(1, w);
  bf16x8 bB0 = WFRAG(0, w + 16), bB1 = WFRAG(1, w + 16);

  // ---- Phase A: stage x write-optimally. Group g in [0,2304): dest = &xs[g*8]
  // (one 16B LDS write, lane-linear -> conflict-free). Group-level branch keeps
  // all loads unconditional and provably in-bounds.
  {
    const float* xw = x + (size_t)win * (NTOK * D1);
    for (int g = tid; g < 2304; g += 1024) {
      int row  = ((g >> 6) & 3) * 16 + (g & 15);
      int col0 = (g >> 8) * 32 + ((g >> 4) & 3) * 8;
      const float* src = xw + row * D1 + col0;
      bf16x8 pk;
      if (col0 <= 248) {
#pragma unroll
        for (int jj = 0; jj < 8; ++jj) pk[jj] = f2b(src[jj]);
      } else if (col0 == 256) {
        pk[0] = f2b(src[0]);
#pragma unroll
        for (int jj = 1; jj < 8; ++jj) pk[jj] = 0;
      } else {
#pragma unroll
        for (int jj = 0; jj < 8; ++jj) pk[jj] = 0;
      }
      *(bf16x8*)&xs[g * 8] = pk;
    }
  }
  for (int i = tid; i < 64 * DS_STRIDE; i += 1024) dsum[i] = 0.f;
  __syncthreads();   // S1

  // ---- Phase B: C = xs[64x288] @ Wcat[288x784]. Two nt-passes, acc[2][4] (32 AGPR),
  // 2-deep global B-frag prefetch + 1-deep LDS A-frag prefetch.
  {
    // ================= pass 0: ntA = w (-> Q), ntB = w+16 (-> K) =================
    f32x4 acc[2][4];
#pragma unroll
    for (int t = 0; t < 2; ++t)
#pragma unroll
      for (int mt = 0; mt < 4; ++mt) acc[t][mt] = f32x4{0.f, 0.f, 0.f, 0.f};

    bf16x8 a_c[4];
#pragma unroll
    for (int mt = 0; mt < 4; ++mt)
      a_c[mt] = *(const bf16x8*)&xs[mt * 512 + lane * 8];

#pragma unroll
    for (int kt = 0; kt < KT; ++kt) {
      bf16x8 bA2{}, bB2{};
      if (kt + 2 < KT) {
        bA2 = WFRAG(kt + 2, w);
        bB2 = WFRAG(kt + 2, w + 16);
      }
      bf16x8 a_n[4];
      if (kt + 1 < KT) {
#pragma unroll
        for (int mt = 0; mt < 4; ++mt)
          a_n[mt] = *(const bf16x8*)&xs[((kt + 1) * 4 + mt) * 512 + lane * 8];
      }
#pragma unroll
      for (int mt = 0; mt < 4; ++mt) acc[0][mt] = mfma16(a_c[mt], bA0, acc[0][mt]);
#pragma unroll
      for (int mt = 0; mt < 4; ++mt) acc[1][mt] = mfma16(a_c[mt], bB0, acc[1][mt]);
      bA0 = bA1; bA1 = bA2; bB0 = bB1; bB1 = bB2;
      if (kt + 1 < KT) {
#pragma unroll
        for (int mt = 0; mt < 4; ++mt) a_c[mt] = a_n[mt];
      }
    }

    // Issue pass-1 prefetch now (overlaps pass-0 epilogue LDS writes).
    bf16x8 cA0 = WFRAG(0, w + 32), cA1 = WFRAG(1, w + 32);
    bf16x8 cB0{}, cB1{};
    if (w == 0) { cB0 = WFRAG(0, 48); cB1 = WFRAG(1, 48); }

    // pass-0 epilogue: Q (acc[0]) and K (acc[1]), frag-linear.
    {
      int cq = (2 * w + (m >> 3)) & 3;
      int jj = m & 7;
      int fb = (w >> 1) * 4;
#pragma unroll
      for (int mt = 0; mt < 4; ++mt)
#pragma unroll
        for (int r = 0; r < 4; ++r)
          qs[(fb + mt) * 512 + (cq * 16 + 4 * q + r) * 8 + jj] = f2b(acc[0][mt][r]);
#pragma unroll
      for (int mt = 0; mt < 4; ++mt)
#pragma unroll
        for (int r = 0; r < 4; ++r)
          ks[(fb + mt) * 512 + (cq * 16 + 4 * q + r) * 8 + jj] = f2b(acc[1][mt][r]);
    }

    // ================= pass 1: ntA = w+32 (-> V), ntB = 48 (w==0 -> depth) =================
#pragma unroll
    for (int t = 0; t < 2; ++t)
#pragma unroll
      for (int mt = 0; mt < 4; ++mt) acc[t][mt] = f32x4{0.f, 0.f, 0.f, 0.f};

#pragma unroll
    for (int mt = 0; mt < 4; ++mt)
      a_c[mt] = *(const bf16x8*)&xs[mt * 512 + lane * 8];

#pragma unroll
    for (int kt = 0; kt < KT; ++kt) {
      bf16x8 cA2{}, cB2{};
      if (kt + 2 < KT) {
        cA2 = WFRAG(kt + 2, w + 32);
        if (w == 0) cB2 = WFRAG(kt + 2, 48);
      }
      bf16x8 a_n[4];
      if (kt + 1 < KT) {
#pragma unroll
        for (int mt = 0; mt < 4; ++mt)
          a_n[mt] = *(const bf16x8*)&xs[((kt + 1) * 4 + mt) * 512 + lane * 8];
      }
#pragma unroll
      for (int mt = 0; mt < 4; ++mt) acc[0][mt] = mfma16(a_c[mt], cA0, acc[0][mt]);
      if (w == 0) {
#pragma unroll
        for (int mt = 0; mt < 4; ++mt) acc[1][mt] = mfma16(a_c[mt], cB0, acc[1][mt]);
      }
      cA0 = cA1; cA1 = cA2; cB0 = cB1; cB1 = cB2;
      if (kt + 1 < KT) {
#pragma unroll
        for (int mt = 0; mt < 4; ++mt) a_c[mt] = a_n[mt];
      }
    }

    // pass-1 epilogue: V B-frag-linear (proven layout)
#pragma unroll
    for (int mt = 0; mt < 4; ++mt) {
      int frag = w * 2 + (mt >> 1);
      int q2 = (2 * mt + (q >> 1)) & 3;
      int j0 = 4 * (q & 1);
      s16x4 pk;
#pragma unroll
      for (int r = 0; r < 4; ++r) pk[r] = f2b(acc[0][mt][r]);
      *(s16x4*)&vs[frag * 512 + (q2 * 16 + m) * 8 + j0] = pk;
    }
    // depth cols 768..770 (w==0 only)
    if (w == 0 && m < 3) {
      float* dst = (m == 0) ? qd_s : (m == 1) ? kd_s : vd_s;
#pragma unroll
      for (int mt = 0; mt < 4; ++mt)
#pragma unroll
        for (int r = 0; r < 4; ++r)
          dst[16 * mt + 4 * q + r] = acc[1][mt][r];
    }
  }
  __syncthreads();   // S2

  // ---- Phase C: wave = (rw = w&3 row tile, hp = w>>2 head pair {2hp, 2hp+1}).
  const int rw = w & 3;
  const int hp = w >> 2;

  bf16x8 aq[2];
#pragma unroll
  for (int hh = 0; hh < 2; ++hh)
    aq[hh] = *(const bf16x8*)&qs[(((2 * hp + hh) * 4 + rw)) * 512 + lane * 8];

  float gate[4][4], ssum[4][4];
  {
    float qd_r[4], kd_c[4];
#pragma unroll
    for (int r = 0; r < 4; ++r) qd_r[r] = qd_s[16 * rw + 4 * q + r];
#pragma unroll
    for (int nt = 0; nt < 4; ++nt) kd_c[nt] = kd_s[16 * nt + m];
#pragma unroll
    for (int nt = 0; nt < 4; ++nt)
#pragma unroll
      for (int r = 0; r < 4; ++r) {
        float t = qd_r[r] * kd_c[nt];
        gate[nt][r] = 1.f / (1.f + __expf(-t));
        ssum[nt][r] = 0.f;
      }
  }
  __syncthreads();   // S3 (qs dead -> at overlay live; oc (over xs) writable)

  short* atw = (short*)(smem + QS2_OFF) + w * (16 * AT_STRIDE);

#pragma unroll
  for (int hh = 0; hh < 2; ++hh) {
    int h = 2 * hp + hh;
    f32x4 sv[4];
#pragma unroll
    for (int nt = 0; nt < 4; ++nt) {
      bf16x8 bk = *(const bf16x8*)&ks[(h * 4 + nt) * 512 + lane * 8];
      f32x4 z = {0.f, 0.f, 0.f, 0.f};
      sv[nt] = mfma16(aq[hh], bk, z);
    }
    float sm[4][4], mx[4], sum[4];
#pragma unroll
    for (int r = 0; r < 4; ++r) mx[r] = -3.4e38f;
#pragma unroll
    for (int nt = 0; nt < 4; ++nt)
#pragma unroll
      for (int r = 0; r < 4; ++r) {
        float s = sv[nt][r] * gate[nt][r];
        ssum[nt][r] += s;
        sm[nt][r] = s;
        mx[r] = fmaxf(mx[r], s);
      }
#pragma unroll
    for (int r = 0; r < 4; ++r) {
#pragma unroll
      for (int msk = 1; msk < 16; msk <<= 1)
        mx[r] = fmaxf(mx[r], __shfl_xor(mx[r], msk));
      sum[r] = 0.f;
    }
#pragma unroll
    for (int nt = 0; nt < 4; ++nt)
#pragma unroll
      for (int r = 0; r < 4; ++r) {
        float p = __expf(sm[nt][r] - mx[r]);
        sm[nt][r] = p;
        sum[r] += p;
      }
#pragma unroll
    for (int r = 0; r < 4; ++r) {
#pragma unroll
      for (int msk = 1; msk < 16; msk <<= 1)
        sum[r] += __shfl_xor(sum[r], msk);
      sum[r] = 1.f / sum[r];
    }
#pragma unroll
    for (int nt = 0; nt < 4; ++nt)
#pragma unroll
      for (int r = 0; r < 4; ++r)
        atw[(4 * q + r) * AT_STRIDE + 16 * nt + m] = f2b(sm[nt][r] * sum[r]);

    // A-frags of attn (wave-private LDS round trip)
    s16x4 l0 = *(const s16x4*)&atw[m * AT_STRIDE + q8];
    s16x4 l1 = *(const s16x4*)&atw[m * AT_STRIDE + q8 + 4];
    s16x4 l2 = *(const s16x4*)&atw[m * AT_STRIDE + 32 + q8];
    s16x4 l3 = *(const s16x4*)&atw[m * AT_STRIDE + 32 + q8 + 4];
    bf16x8 a0, a1;
#pragma unroll
    for (int j = 0; j < 4; ++j) { a0[j] = l0[j]; a0[4 + j] = l1[j]; a1[j] = l2[j]; a1[4 + j] = l3[j]; }

#pragma unroll
    for (int ntv = 0; ntv < 2; ++ntv) {
      bf16x8 bv0 = *(const bf16x8*)&vs[(((2 * h + ntv) * 2) + 0) * 512 + lane * 8];
      bf16x8 bv1 = *(const bf16x8*)&vs[(((2 * h + ntv) * 2) + 1) * 512 + lane * 8];
      f32x4 o = {0.f, 0.f, 0.f, 0.f};
      o = mfma16(a0, bv0, o);
      o = mfma16(a1, bv1, o);
      // oc frag-linear write: row=16rw+4q+r, col=32h+16ntv+m
      int cq2 = (2 * ntv + (m >> 3)) & 3;
#pragma unroll
      for (int r = 0; r < 4; ++r)
        oc[(h * 4 + rw) * 512 + (cq2 * 16 + 4 * q + r) * 8 + (m & 7)] = f2b(o[r]);
    }
  }

  // head-sum reduction across the 4 hp-waves sharing rw
#pragma unroll
  for (int nt = 0; nt < 4; ++nt)
#pragma unroll
    for (int r = 0; r < 4; ++r)
      atomicAdd(&dsum[(16 * rw + 4 * q + r) * DS_STRIDE + 16 * nt + m], ssum[nt][r]);
  __syncthreads();   // S5

  if (hp == 0) {     // attn_d softmax + out_d for rows 16rw..16rw+15
    float sd[4][4], mx[4], sum[4];
#pragma unroll
    for (int nt = 0; nt < 4; ++nt)
#pragma unroll
      for (int r = 0; r < 4; ++r)
        sd[nt][r] = dsum[(16 * rw + 4 * q + r) * DS_STRIDE + 16 * nt + m];
#pragma unroll
    for (int r = 0; r < 4; ++r) mx[r] = -3.4e38f;
#pragma unroll
    for (int nt = 0; nt < 4; ++nt)
#pragma unroll
      for (int r = 0; r < 4; ++r) mx[r] = fmaxf(mx[r], sd[nt][r]);
#pragma unroll
    for (int r = 0; r < 4; ++r) {
#pragma unroll
      for (int msk = 1; msk < 16; msk <<= 1)
        mx[r] = fmaxf(mx[r], __shfl_xor(mx[r], msk));
      sum[r] = 0.f;
    }
#pragma unroll
    for (int nt = 0; nt < 4; ++nt)
#pragma unroll
      for (int r = 0; r < 4; ++r) {
        sd[nt][r] = __expf(sd[nt][r] - mx[r]);
        sum[r] += sd[nt][r];
      }
#pragma unroll
    for (int r = 0; r < 4; ++r) {
#pragma unroll
      for (int msk = 1; msk < 16; msk <<= 1)
        sum[r] += __shfl_xor(sum[r], msk);
      sum[r] = 1.f / sum[r];
    }
    float vd_c[4];
#pragma unroll
    for (int nt = 0; nt < 4; ++nt) vd_c[nt] = vd_s[16 * nt + m];
    float ov[4] = {0.f, 0.f, 0.f, 0.f};
#pragma unroll
    for (int nt = 0; nt < 4; ++nt)
#pragma unroll
      for (int r = 0; r < 4; ++r) ov[r] += sd[nt][r] * vd_c[nt];
#pragma unroll
    for (int r = 0; r < 4; ++r) {
#pragma unroll
      for (int msk = 1; msk < 16; msk <<= 1)
        ov[r] += __shfl_xor(ov[r], msk);
    }
    if (m == 0) {
      // col 256 -> frag 32+rw, cq=0, j=0
#pragma unroll
      for (int r = 0; r < 4; ++r)
        oc[(32 + rw) * 512 + (4 * q + r) * 8] = f2b(ov[r] * sum[r]);
    }
  }

  // Pre-issue phase-D B-frags (kt=0,1) BEFORE S6: barrier drain hides their latency.
  bf16x8 dA0 = OFRAG(0, w), dA1 = OFRAG(1, w);
  bf16x8 dB0{}, dB1{};
  if (w == 0) { dB0 = OFRAG(0, 16); dB1 = OFRAG(1, 16); }
  __syncthreads();   // S6

  // ---- Phase D: out = oc[64x288] @ Wout[288x272]; wave w owns nt {w, 16 (w==0)}.
  // 2-deep global prefetch + 1-deep LDS A-frag prefetch.
  {
    f32x4 acc2[2][4];
#pragma unroll
    for (int t = 0; t < 2; ++t)
#pragma unroll
      for (int mt = 0; mt < 4; ++mt) acc2[t][mt] = f32x4{0.f, 0.f, 0.f, 0.f};

    bf16x8 ao_c[4];
#pragma unroll
    for (int mt = 0; mt < 4; ++mt)
      ao_c[mt] = *(const bf16x8*)&oc[mt * 512 + lane * 8];

#pragma unroll
    for (int kt = 0; kt < KT; ++kt) {
      bf16x8 dA2{}, dB2{};
      if (kt + 2 < KT) {
        dA2 = OFRAG(kt + 2, w);
        if (w == 0) dB2 = OFRAG(kt + 2, 16);
      }
      bf16x8 ao_n[4];
      if (kt + 1 < KT) {
#pragma unroll
        for (int mt = 0; mt < 4; ++mt)
          ao_n[mt] = *(const bf16x8*)&oc[((kt + 1) * 4 + mt) * 512 + lane * 8];
      }
#pragma unroll
      for (int mt = 0; mt < 4; ++mt) acc2[0][mt] = mfma16(ao_c[mt], dA0, acc2[0][mt]);
      if (w == 0) {
#pragma unroll
        for (int mt = 0; mt < 4; ++mt) acc2[1][mt] = mfma16(ao_c[mt], dB0, acc2[1][mt]);
      }
      dA0 = dA1; dA1 = dA2; dB0 = dB1; dB1 = dB2;
      if (kt + 1 < KT) {
#pragma unroll
        for (int mt = 0; mt < 4; ++mt) ao_c[mt] = ao_n[mt];
      }
    }

    // epilogue: t=0 -> n = 16w+m (always < 256); t=1 (w==0) -> n = 256 (m==0 only)
    {
      int n = 16 * w + m;
#pragma unroll
      for (int mt = 0; mt < 4; ++mt)
#pragma unroll
        for (int r = 0; r < 4; ++r)
          out[((size_t)win * NTOK + 16 * mt + 4 * q + r) * D1 + n] = acc2[0][mt][r];
    }
    if (w == 0 && m == 0) {
#pragma unroll
      for (int mt = 0; mt < 4; ++mt)
#pragma unroll
        for (int r = 0; r < 4; ++r)
          out[((size_t)win * NTOK + 16 * mt + 4 * q + r) * D1 + 256] = acc2[1][mt][r];
    }
  }
}

extern "C" void kernel_launch(void* const* d_in, const int* in_sizes, int n_in,
                              void* d_out, int out_size, void* d_ws, size_t ws_size,
                              hipStream_t stream) {
  (void)n_in; (void)out_size; (void)ws_size;
  const float* x    = (const float*)d_in[0];
  const float* Wqv  = (const float*)d_in[1];
  const float* Wkv  = (const float*)d_in[2];
  const float* Wvv  = (const float*)d_in[3];
  const float* Wqd  = (const float*)d_in[4];
  const float* Wkd  = (const float*)d_in[5];
  const float* Wvd  = (const float*)d_in[6];
  const float* Wout = (const float*)d_in[7];
  float* out = (float*)d_out;

  short* wcatp = (short*)d_ws;                  // 608,256 B total for weights
  short* woutp = wcatp + WCAT_ELEMS;

  int nwin = in_sizes[0] / (NTOK * D1);         // 2048

  int prep_blocks = (WCAT_ELEMS + WOUT_ELEMS) / 256;   // 1188, exact
  prep_weights<<<prep_blocks, 256, 0, stream>>>(Wqv, Wkv, Wvv, Wqd, Wkd, Wvd, Wout, wcatp, woutp);

  hipFuncSetAttribute((const void*)vda_attn2, hipFuncAttributeMaxDynamicSharedMemorySize, LDS2);
  vda_attn2<<<nwin, 1024, LDS2, stream>>>(x, wcatp, woutp, out);
}